// Round 6
// baseline (530.031 us; speedup 1.0000x reference)
//
#include <hip/hip_runtime.h>

#define EMBED 1024
#define BATCH 4
#define SEQ   4096
#define ROWS  (BATCH*SEQ)   // 16384
#define CAP   128           // candidate slots per row (r3-r12 proven)
#define TSCAN_U 1600.0f     // scan margin, unscaled (50 scaled) — r12-proven passing
#define TRES  75.0f         // rescore margin, scaled logits (proven)

typedef __attribute__((ext_vector_type(8))) short bf16x8;
typedef __attribute__((ext_vector_type(4))) float f32x4;

static __device__ __forceinline__ unsigned short f2bf(float x) {
    unsigned u = __float_as_uint(x);
    u = (u + 0x7fffu + ((u >> 16) & 1u)) >> 16;
    return (unsigned short)u;
}
static __device__ __forceinline__ float bf2f(unsigned short h) {
    return __uint_as_float(((unsigned)h) << 16);
}
static __device__ __forceinline__ void split2(float x, unsigned short& hi, unsigned short& lo) {
    hi = f2bf(x);
    lo = f2bf(x - bf2f(hi));
}

// ---- async global->LDS, one 16B segment (4-segment swizzle offsets precomputed by caller) ----
static __device__ __forceinline__ void gll(const unsigned short* g, unsigned short* l) {
    __builtin_amdgcn_global_load_lds(
        (const __attribute__((address_space(1))) unsigned int*)g,
        (__attribute__((address_space(3))) unsigned int*)l, 16, 0, 0);
}
// legacy stagers (prep kernels only)
static __device__ __forceinline__ void stage_tile(unsigned short (*lds)[32],
                                                  const unsigned short* gbase,
                                                  int wave, int lane) {
#pragma unroll
    for (int c = 0; c < 2; c++) {
        int L = wave * 128 + c * 64 + lane;
        int r = L >> 2, s = L & 3;
        int g = (s - (r >> 1)) & 3;
        gll(gbase + (size_t)r * EMBED + g * 8, &lds[r][s * 8]);
    }
}

// ---------------- prep: wv_bar[i] = mean_d Wv[i][d] ----------------
__global__ void k_wvbar(const float* __restrict__ Wv, float* __restrict__ wvbar) {
    int r = blockIdx.x, t = threadIdx.x;
    float s = 0.f;
    for (int c = t; c < EMBED; c += 256) s += Wv[(size_t)r * EMBED + c];
    for (int d = 1; d < 64; d <<= 1) s += __shfl_xor(s, d);
    __shared__ float ws_[4];
    if ((t & 63) == 0) ws_[t >> 6] = s;
    __syncthreads();
    if (t == 0) wvbar[r] = (ws_[0] + ws_[1] + ws_[2] + ws_[3]) * (1.0f / EMBED);
}

// ---------------- prep: row split + vmean + cnt zeroing (fused, one X read) ----------------
__global__ __launch_bounds__(256) void k_xsplit_vmean(
    const float* __restrict__ X, const float* __restrict__ wvbar,
    unsigned short* __restrict__ Xhi, unsigned short* __restrict__ Xlo,
    float* __restrict__ vmean, int* __restrict__ cnt) {
    int row = blockIdx.x, t = threadIdx.x;
    float4 x4 = *(const float4*)(X + (size_t)row * EMBED + t * 4);
    float4 w4 = *(const float4*)(wvbar + t * 4);
    ushort4 h, l;
    split2(x4.x, h.x, l.x); split2(x4.y, h.y, l.y);
    split2(x4.z, h.z, l.z); split2(x4.w, h.w, l.w);
    *(ushort4*)(Xhi + (size_t)row * EMBED + t * 4) = h;
    *(ushort4*)(Xlo + (size_t)row * EMBED + t * 4) = l;
    float s = x4.x * w4.x + x4.y * w4.y + x4.z * w4.z + x4.w * w4.w;
    for (int d = 1; d < 64; d <<= 1) s += __shfl_xor(s, d);
    __shared__ float ws_[4];
    if ((t & 63) == 0) ws_[t >> 6] = s;
    __syncthreads();
    if (t == 0) { vmean[row] = ws_[0] + ws_[1] + ws_[2] + ws_[3]; cnt[row] = 0; }
}

// ---------------- split-bf16 GEMM: C[row][col] = sum_k A[row][k]*B[col][k] ----------------
// r18: all K-loop addressing hoisted. Staging offsets (go,lo) and fragment LDS offsets
// (offM/offN) are loop-invariant; the four buffers are one flat LDS array so the buffer
// select is a compile-time immediate folded into ds_read offset: / the gll dest.
// Saves ~150 VALU-inst/wave/step (was 20% VALUBusy — pipes SUM here, so VALU is wall time).
__global__ __launch_bounds__(256) void k_gemm3(
    const unsigned short* __restrict__ Ahi, const unsigned short* __restrict__ Alo,
    const unsigned short* __restrict__ BThi, const unsigned short* __restrict__ BTlo,
    unsigned short* __restrict__ Chi, unsigned short* __restrict__ Clo) {
    __shared__ unsigned short G[16384];   // Ah|Al|Bh|Bl, 4096 shorts (8 KB) each
    const int Ah_ = 0, Al_ = 4096, Bh_ = 8192, Bl_ = 12288;
    int bx = blockIdx.x;
    int bm = bx >> 3, bn = bx & 7;   // bn == XCD id under round-robin: B-tiles L2-local
    int tid = threadIdx.x, wave = tid >> 6, lane = tid & 63;
    int wm = (wave >> 1) * 64, wn = (wave & 1) * 64;
    int mrow = lane & 15, kq = (lane >> 4) * 8;

    // hoisted staging offsets (4-segment swizzle, r3-proven 0-conflict)
    int L0 = wave * 128 + lane, L1 = L0 + 64;
    int r0 = L0 >> 2, s0 = L0 & 3, g0s = (s0 - (r0 >> 1)) & 3;
    int r1 = L1 >> 2, s1 = L1 & 3, g1s = (s1 - (r1 >> 1)) & 3;
    int go0 = r0 * EMBED + g0s * 8, lo0 = L0 * 8;   // lo = r*32+s*8 = L*8 (shorts)
    int go1 = r1 * EMBED + g1s * 8, lo1 = L1 * 8;

    // hoisted fragment offsets (shorts)
    int offM[4], offN[4];
#pragma unroll
    for (int t = 0; t < 4; t++) {
        int rM = wm + t * 16 + mrow; offM[t] = rM * 32 + ((((kq >> 3) + (rM >> 1)) & 3) * 8);
        int rN = wn + t * 16 + mrow; offN[t] = rN * 32 + ((((kq >> 3) + (rN >> 1)) & 3) * 8);
    }

    f32x4 zero = {0.f, 0.f, 0.f, 0.f};
    f32x4 acc[4][4];
    for (int a = 0; a < 4; a++) for (int b = 0; b < 4; b++) acc[a][b] = zero;

    const unsigned short* Akh = Ahi  + (size_t)(bm * 128) * EMBED;
    const unsigned short* Akl = Alo  + (size_t)(bm * 128) * EMBED;
    const unsigned short* Bkh = BThi + (size_t)(bn * 128) * EMBED;
    const unsigned short* Bkl = BTlo + (size_t)(bn * 128) * EMBED;

    for (int k0 = 0; k0 < EMBED; k0 += 32) {
        __syncthreads();
        gll(Akh + go0, G + Ah_ + lo0); gll(Akh + go1, G + Ah_ + lo1);
        gll(Akl + go0, G + Al_ + lo0); gll(Akl + go1, G + Al_ + lo1);
        gll(Bkh + go0, G + Bh_ + lo0); gll(Bkh + go1, G + Bh_ + lo1);
        gll(Bkl + go0, G + Bl_ + lo0); gll(Bkl + go1, G + Bl_ + lo1);
        __syncthreads();
        bf16x8 ah[4], al[4], bh[4], bl[4];
#pragma unroll
        for (int t = 0; t < 4; t++) {
            ah[t] = *(const bf16x8*)(G + Ah_ + offM[t]);
            al[t] = *(const bf16x8*)(G + Al_ + offM[t]);
            bh[t] = *(const bf16x8*)(G + Bh_ + offN[t]);
            bl[t] = *(const bf16x8*)(G + Bl_ + offN[t]);
        }
#pragma unroll
        for (int mt = 0; mt < 4; mt++)
#pragma unroll
            for (int nt = 0; nt < 4; nt++) {
                acc[mt][nt] = __builtin_amdgcn_mfma_f32_16x16x32_bf16(ah[mt], bh[nt], acc[mt][nt], 0, 0, 0);
                acc[mt][nt] = __builtin_amdgcn_mfma_f32_16x16x32_bf16(ah[mt], bl[nt], acc[mt][nt], 0, 0, 0);
                acc[mt][nt] = __builtin_amdgcn_mfma_f32_16x16x32_bf16(al[mt], bh[nt], acc[mt][nt], 0, 0, 0);
            }
        Akh += 32; Akl += 32; Bkh += 32; Bkl += 32;
    }
#pragma unroll
    for (int mt = 0; mt < 4; mt++)
#pragma unroll
        for (int nt = 0; nt < 4; nt++)
#pragma unroll
            for (int i = 0; i < 4; i++) {
                int row = bm * 128 + wm + mt * 16 + (lane >> 4) * 4 + i;
                int col = bn * 128 + wn + nt * 16 + (lane & 15);
                unsigned short h, l; split2(acc[mt][nt][i], h, l);
                Chi[(size_t)row * EMBED + col] = h;
                Clo[(size_t)row * EMBED + col] = l;
            }
}

// ---------------- scan: 128q x 128k block tile; each wave owns 64q x 64k ----------------
// r13-r17 ledger: dbuf-drain0 null; 3-buf counted vmcnt -> VGPR death; occupancy 41% -> -4%;
// BK=64 2-sub-step -> best (215us); 512-thr counted-vmcnt -> LDS 132KB -> 1 blk/CU -> null.
// Accounting: pipes SUM (MFMA 1860 + LDS 2300 + stage 1000 + VALU 1200 cy/interval ~= 6070
// measured). r18 attacks the VALU term: ALL addressing hoisted out of the K-loop (staging
// go/lo, fragment offA/offB; flat LDS so buffer select is an imm). Structure = r4 verbatim.
__global__ __launch_bounds__(256, 3) void k_scan(
    const unsigned short* __restrict__ Thi, const unsigned short* __restrict__ Xhi,
    int* __restrict__ cnt, int2* __restrict__ cand) {
    __shared__ unsigned short S[16384];   // ThA|KhA|ThB|KhB, 4096 shorts each (33 KB total)
    __shared__ float rowmax_[2][2][64];
    const int ThA_ = 0, KhA_ = 4096, ThB_ = 8192, KhB_ = 12288;
    // XCD-aware map: XCD = bid%8; each XCD owns 4 fixed 128-key tiles per batch.
    int bid = blockIdx.x;            // 0..4095
    int x   = bid & 7;
    int i   = bid >> 3;
    int kbi = i & 3;
    int qb  = (i >> 2) & 31;
    int b   = i >> 7;
    int kb  = x * 4 + kbi;
    int tid = threadIdx.x, wave = tid >> 6, lane = tid & 63;
    int wr = wave >> 1, wc = wave & 1;
    int wq = wr * 64, wk = wc * 64;
    int mrow = lane & 15, kq = (lane >> 4) * 8;
    size_t qrow0 = (size_t)b * SEQ + (size_t)qb * 128;
    size_t krow0 = (size_t)b * SEQ + (size_t)kb * 128;
    const unsigned short* Tk = Thi + qrow0 * EMBED;
    const unsigned short* Xk = Xhi + krow0 * EMBED;

    // hoisted staging offsets
    int L0 = wave * 128 + lane, L1 = L0 + 64;
    int r0 = L0 >> 2, s0 = L0 & 3, g0s = (s0 - (r0 >> 1)) & 3;
    int r1 = L1 >> 2, s1 = L1 & 3, g1s = (s1 - (r1 >> 1)) & 3;
    int go0 = r0 * EMBED + g0s * 8, lo0 = L0 * 8;
    int go1 = r1 * EMBED + g1s * 8, lo1 = L1 * 8;

    // hoisted fragment offsets (shorts)
    int offA[4], offB[4];
#pragma unroll
    for (int t = 0; t < 4; t++) {
        int rA = wq + t * 16 + mrow; offA[t] = rA * 32 + ((((kq >> 3) + (rA >> 1)) & 3) * 8);
        int rB = wk + t * 16 + mrow; offB[t] = rB * 32 + ((((kq >> 3) + (rB >> 1)) & 3) * 8);
    }

    f32x4 zero = {0.f, 0.f, 0.f, 0.f};
    f32x4 acc[4][4];
    for (int a = 0; a < 4; a++) for (int c = 0; c < 4; c++) acc[a][c] = zero;

    for (int k0 = 0; k0 < EMBED; k0 += 64) {
        __syncthreads();
        gll(Tk + go0,      S + ThA_ + lo0); gll(Tk + go1,      S + ThA_ + lo1);
        gll(Xk + go0,      S + KhA_ + lo0); gll(Xk + go1,      S + KhA_ + lo1);
        gll(Tk + 32 + go0, S + ThB_ + lo0); gll(Tk + 32 + go1, S + ThB_ + lo1);
        gll(Xk + 32 + go0, S + KhB_ + lo0); gll(Xk + 32 + go1, S + KhB_ + lo1);
        __syncthreads();
        {   // sub-step A (k0..k0+31)
            bf16x8 ah[4], bh[4];
#pragma unroll
            for (int t = 0; t < 4; t++) {
                ah[t] = *(const bf16x8*)(S + ThA_ + offA[t]);
                bh[t] = *(const bf16x8*)(S + KhA_ + offB[t]);
            }
#pragma unroll
            for (int mt = 0; mt < 4; mt++)
#pragma unroll
                for (int nt = 0; nt < 4; nt++)
                    acc[mt][nt] = __builtin_amdgcn_mfma_f32_16x16x32_bf16(ah[mt], bh[nt], acc[mt][nt], 0, 0, 0);
        }
        {   // sub-step B (k0+32..k0+63)
            bf16x8 ah[4], bh[4];
#pragma unroll
            for (int t = 0; t < 4; t++) {
                ah[t] = *(const bf16x8*)(S + ThB_ + offA[t]);
                bh[t] = *(const bf16x8*)(S + KhB_ + offB[t]);
            }
#pragma unroll
            for (int mt = 0; mt < 4; mt++)
#pragma unroll
                for (int nt = 0; nt < 4; nt++)
                    acc[mt][nt] = __builtin_amdgcn_mfma_f32_16x16x32_bf16(ah[mt], bh[nt], acc[mt][nt], 0, 0, 0);
        }
        Tk += 64; Xk += 64;
    }

    // ---- epilogue pass 1: per-row max over this wave's 64 keys -> LDS exchange ----
#pragma unroll
    for (int mt = 0; mt < 4; mt++)
#pragma unroll
        for (int i2 = 0; i2 < 4; i2++) {
            float v = -INFINITY;
#pragma unroll
            for (int nt = 0; nt < 4; nt++) v = fmaxf(v, acc[mt][nt][i2]);
#pragma unroll
            for (int d = 1; d < 16; d <<= 1) v = fmaxf(v, __shfl_xor(v, d));
            if ((lane & 15) == 0) {
                int lr = mt * 16 + (lane >> 4) * 4 + i2;
                rowmax_[wc][wr][lr] = v;
            }
        }
    __syncthreads();
    // ---- epilogue pass 2: threshold over the block's FULL 128 keys; emit candidates ----
#pragma unroll
    for (int mt = 0; mt < 4; mt++)
#pragma unroll
        for (int i2 = 0; i2 < 4; i2++) {
            int lr = mt * 16 + (lane >> 4) * 4 + i2;
            float th = fmaxf(rowmax_[0][wr][lr], rowmax_[1][wr][lr]) - TSCAN_U;
            int grow = (int)qrow0 + wq + lr;
#pragma unroll
            for (int nt = 0; nt < 4; nt++) {
                float s = acc[mt][nt][i2];
                if (s >= th) {
                    int gcol = (int)krow0 + wk + nt * 16 + (lane & 15);
                    int idx = atomicAdd(&cnt[grow], 1);
                    if (idx < CAP)
                        cand[(size_t)grow * CAP + idx] = make_int2(gcol, __float_as_int(s * 0.03125f));
                }
            }
        }
}

// ---------------- rescore: 4 rows per block, one wave per row, barrier-free ----------------
__global__ __launch_bounds__(256) void k_rescore(
    const unsigned short* __restrict__ Thi, const unsigned short* __restrict__ Tlo,
    const float* __restrict__ X, const float* __restrict__ vmean,
    const int* __restrict__ cnt, const int2* __restrict__ cand,
    float* __restrict__ out) {
    int wave = threadIdx.x >> 6, lane = threadIdx.x & 63;
    int row = blockIdx.x * 4 + wave;
    int c = cnt[row]; if (c > CAP) c = CAP;
    const int2* cl = cand + (size_t)row * CAP;

    float smax = -INFINITY;
    for (int j = lane; j < c; j += 64) smax = fmaxf(smax, __int_as_float(cl[j].y));
    for (int d = 1; d < 64; d <<= 1) smax = fmaxf(smax, __shfl_xor(smax, d));
    float th = smax - TRES;

    float q[16];
    {
        const unsigned short* qh = Thi + (size_t)row * EMBED + lane * 16;
        const unsigned short* ql = Tlo + (size_t)row * EMBED + lane * 16;
        bf16x8 h0 = *(const bf16x8*)qh, h1 = *(const bf16x8*)(qh + 8);
        bf16x8 l0 = *(const bf16x8*)ql, l1 = *(const bf16x8*)(ql + 8);
#pragma unroll
        for (int i = 0; i < 8; i++) {
            q[i]     = bf2f((unsigned short)h0[i]) + bf2f((unsigned short)l0[i]);
            q[i + 8] = bf2f((unsigned short)h1[i]) + bf2f((unsigned short)l1[i]);
        }
    }

    __shared__ int   sm_[4][CAP];
    __shared__ float sl_[4][CAP];
    __shared__ int   ns_[4];
    if (lane == 0) ns_[wave] = 0;
    for (int j = lane; j < c; j += 64) {
        int2 p = cl[j];
        if (__int_as_float(p.y) >= th) {
            int idx = atomicAdd(&ns_[wave], 1);
            sm_[wave][idx] = p.x;
        }
    }
    int ns = ns_[wave];
    for (int t = 0; t < ns; t++) {
        int m = sm_[wave][t];
        const float* xr = X + (size_t)m * EMBED + lane * 16;
        float4 a0 = *(const float4*)(xr);
        float4 a1 = *(const float4*)(xr + 4);
        float4 a2 = *(const float4*)(xr + 8);
        float4 a3 = *(const float4*)(xr + 12);
        float dp = q[0]*a0.x + q[1]*a0.y + q[2]*a0.z + q[3]*a0.w
                 + q[4]*a1.x + q[5]*a1.y + q[6]*a1.z + q[7]*a1.w
                 + q[8]*a2.x + q[9]*a2.y + q[10]*a2.z + q[11]*a2.w
                 + q[12]*a3.x + q[13]*a3.y + q[14]*a3.z + q[15]*a3.w;
        for (int d = 1; d < 64; d <<= 1) dp += __shfl_xor(dp, d);
        if (lane == 0) sl_[wave][t] = dp * 0.03125f;
    }
    if (lane == 0) {
        float lm = -INFINITY;
        for (int t = 0; t < ns; t++) lm = fmaxf(lm, sl_[wave][t]);
        float den = 0.f, num = 0.f;
        for (int t = 0; t < ns; t++) {
            float e = __expf(sl_[wave][t] - lm);
            den += e;
            num += e * vmean[sm_[wave][t]];
        }
        out[row] = num / den;
    }
}

extern "C" void kernel_launch(void* const* d_in, const int* in_sizes, int n_in,
                              void* d_out, int out_size, void* d_ws, size_t ws_size,
                              hipStream_t stream) {
    const float* X  = (const float*)d_in[0];
    const float* Wq = (const float*)d_in[1];
    const float* Wk = (const float*)d_in[2];
    const float* Wv = (const float*)d_in[3];
    float* out = (float*)d_out;

    char* p = (char*)d_ws;
    auto alloc = [&](size_t bytes) -> void* {
        void* q = (void*)p;
        p += (bytes + 255) & ~(size_t)255;
        return q;
    };
    unsigned short* Wqhi = (unsigned short*)alloc((size_t)EMBED * EMBED * 2);
    unsigned short* Wqlo = (unsigned short*)alloc((size_t)EMBED * EMBED * 2);
    unsigned short* Wkhi = (unsigned short*)alloc((size_t)EMBED * EMBED * 2);
    unsigned short* Wklo = (unsigned short*)alloc((size_t)EMBED * EMBED * 2);
    unsigned short* MThi = (unsigned short*)alloc((size_t)EMBED * EMBED * 2);
    unsigned short* MTlo = (unsigned short*)alloc((size_t)EMBED * EMBED * 2);
    unsigned short* Xhi  = (unsigned short*)alloc((size_t)ROWS * EMBED * 2);
    unsigned short* Xlo  = (unsigned short*)alloc((size_t)ROWS * EMBED * 2);
    unsigned short* Thi  = (unsigned short*)alloc((size_t)ROWS * EMBED * 2);
    unsigned short* Tlo  = (unsigned short*)alloc((size_t)ROWS * EMBED * 2);
    float* wvbar = (float*)alloc(EMBED * 4);
    float* vmean = (float*)alloc((size_t)ROWS * 4);
    int*   cnt   = (int*)alloc((size_t)ROWS * 4);
    int2*  cand  = (int2*)alloc((size_t)ROWS * CAP * 8);

    k_wvbar<<<EMBED, 256, 0, stream>>>(Wv, wvbar);
    // Row splits of the ORIGINAL Wq/Wk (M contraction is over the contiguous output dim).
    // vmean/cnt args are scratch here (rows 0..1023; real run below overwrites all rows).
    k_xsplit_vmean<<<EMBED, 256, 0, stream>>>(Wq, wvbar, Wqhi, Wqlo, vmean, cnt);
    k_xsplit_vmean<<<EMBED, 256, 0, stream>>>(Wk, wvbar, Wkhi, Wklo, vmean, cnt);
    // M^T[b][a] = sum_n Wk[b][n]*Wq[a][n]
    k_gemm3<<<64, 256, 0, stream>>>(Wkhi, Wklo, Wqhi, Wqlo, MThi, MTlo);
    k_xsplit_vmean<<<ROWS, 256, 0, stream>>>(X, wvbar, Xhi, Xlo, vmean, cnt);  // real vmean + cnt=0
    k_gemm3<<<1024, 256, 0, stream>>>(Xhi, Xlo, MThi, MTlo, Thi, Tlo);         // T = X.M
    k_scan<<<4096, 256, 0, stream>>>(Thi, Xhi, cnt, cand);
    k_rescore<<<ROWS / 4, 256, 0, stream>>>(Thi, Tlo, X, vmean, cnt, cand, out);
}

// Round 7
// 496.231 us; speedup vs baseline: 1.0681x; 1.0681x over previous
//
#include <hip/hip_runtime.h>

#define EMBED 1024
#define BATCH 4
#define SEQ   4096
#define ROWS  (BATCH*SEQ)   // 16384
#define CAP   128           // candidate slots per row (r3-r12 proven)
#define TSCAN_U 1600.0f     // scan margin, unscaled (50 scaled) — r12-proven passing
#define TRES  75.0f         // rescore margin, scaled logits (proven)

typedef __attribute__((ext_vector_type(8))) short bf16x8;
typedef __attribute__((ext_vector_type(4))) float f32x4;

static __device__ __forceinline__ unsigned short f2bf(float x) {
    unsigned u = __float_as_uint(x);
    u = (u + 0x7fffu + ((u >> 16) & 1u)) >> 16;
    return (unsigned short)u;
}
static __device__ __forceinline__ float bf2f(unsigned short h) {
    return __uint_as_float(((unsigned)h) << 16);
}
static __device__ __forceinline__ void split2(float x, unsigned short& hi, unsigned short& lo) {
    hi = f2bf(x);
    lo = f2bf(x - bf2f(hi));
}

// ---- async global->LDS, one 16B segment ----
static __device__ __forceinline__ void gll(const unsigned short* g, unsigned short* l) {
    __builtin_amdgcn_global_load_lds(
        (const __attribute__((address_space(1))) unsigned int*)g,
        (__attribute__((address_space(3))) unsigned int*)l, 16, 0, 0);
}
// ---- 128x32-short tile stager, 4-segment swizzle (r3-proven, 0 conflicts) ----
static __device__ __forceinline__ void stage_tile(unsigned short (*lds)[32],
                                                  const unsigned short* gbase,
                                                  int wave, int lane) {
#pragma unroll
    for (int c = 0; c < 2; c++) {
        int L = wave * 128 + c * 64 + lane;
        int r = L >> 2, s = L & 3;
        int g = (s - (r >> 1)) & 3;
        gll(gbase + (size_t)r * EMBED + g * 8, &lds[r][s * 8]);
    }
}
static __device__ __forceinline__ bf16x8 read_frag(const unsigned short (*lds)[32], int r, int kq) {
    int s = ((kq >> 3) + (r >> 1)) & 3;
    return *(const bf16x8*)&lds[r][s * 8];
}

// ---------------- prep: wv_bar[i] = mean_d Wv[i][d] ----------------
__global__ void k_wvbar(const float* __restrict__ Wv, float* __restrict__ wvbar) {
    int r = blockIdx.x, t = threadIdx.x;
    float s = 0.f;
    for (int c = t; c < EMBED; c += 256) s += Wv[(size_t)r * EMBED + c];
    for (int d = 1; d < 64; d <<= 1) s += __shfl_xor(s, d);
    __shared__ float ws_[4];
    if ((t & 63) == 0) ws_[t >> 6] = s;
    __syncthreads();
    if (t == 0) wvbar[r] = (ws_[0] + ws_[1] + ws_[2] + ws_[3]) * (1.0f / EMBED);
}

// ---------------- prep: row split + vmean + cnt zeroing (fused, one X read) ----------------
__global__ __launch_bounds__(256) void k_xsplit_vmean(
    const float* __restrict__ X, const float* __restrict__ wvbar,
    unsigned short* __restrict__ Xhi, unsigned short* __restrict__ Xlo,
    float* __restrict__ vmean, int* __restrict__ cnt) {
    int row = blockIdx.x, t = threadIdx.x;
    float4 x4 = *(const float4*)(X + (size_t)row * EMBED + t * 4);
    float4 w4 = *(const float4*)(wvbar + t * 4);
    ushort4 h, l;
    split2(x4.x, h.x, l.x); split2(x4.y, h.y, l.y);
    split2(x4.z, h.z, l.z); split2(x4.w, h.w, l.w);
    *(ushort4*)(Xhi + (size_t)row * EMBED + t * 4) = h;
    *(ushort4*)(Xlo + (size_t)row * EMBED + t * 4) = l;
    float s = x4.x * w4.x + x4.y * w4.y + x4.z * w4.z + x4.w * w4.w;
    for (int d = 1; d < 64; d <<= 1) s += __shfl_xor(s, d);
    __shared__ float ws_[4];
    if ((t & 63) == 0) ws_[t >> 6] = s;
    __syncthreads();
    if (t == 0) { vmean[row] = ws_[0] + ws_[1] + ws_[2] + ws_[3]; cnt[row] = 0; }
}

// ---------------- split-bf16 GEMM: C[row][col] = sum_k A[row][k]*B[col][k] (r4-proven) ----------------
__global__ __launch_bounds__(256) void k_gemm3(
    const unsigned short* __restrict__ Ahi, const unsigned short* __restrict__ Alo,
    const unsigned short* __restrict__ BThi, const unsigned short* __restrict__ BTlo,
    unsigned short* __restrict__ Chi, unsigned short* __restrict__ Clo) {
    __shared__ unsigned short Ah[128][32], Al[128][32], Bh[128][32], Bl[128][32];
    int bx = blockIdx.x;
    int bm = bx >> 3, bn = bx & 7;   // bn == XCD id under round-robin: B-tiles L2-local
    int tid = threadIdx.x, wave = tid >> 6, lane = tid & 63;
    int wm = (wave >> 1) * 64, wn = (wave & 1) * 64;
    int mrow = lane & 15, kq = (lane >> 4) * 8;

    f32x4 zero = {0.f, 0.f, 0.f, 0.f};
    f32x4 acc[4][4];
    for (int a = 0; a < 4; a++) for (int b = 0; b < 4; b++) acc[a][b] = zero;

    const unsigned short* Abase_h = Ahi + (size_t)(bm * 128) * EMBED;
    const unsigned short* Abase_l = Alo + (size_t)(bm * 128) * EMBED;
    const unsigned short* Bbase_h = BThi + (size_t)(bn * 128) * EMBED;
    const unsigned short* Bbase_l = BTlo + (size_t)(bn * 128) * EMBED;

    for (int k0 = 0; k0 < EMBED; k0 += 32) {
        __syncthreads();
        stage_tile(Ah, Abase_h + k0, wave, lane);
        stage_tile(Al, Abase_l + k0, wave, lane);
        stage_tile(Bh, Bbase_h + k0, wave, lane);
        stage_tile(Bl, Bbase_l + k0, wave, lane);
        __syncthreads();
        bf16x8 ah[4], al[4], bh[4], bl[4];
#pragma unroll
        for (int t = 0; t < 4; t++) {
            ah[t] = read_frag(Ah, wm + t * 16 + mrow, kq);
            al[t] = read_frag(Al, wm + t * 16 + mrow, kq);
            bh[t] = read_frag(Bh, wn + t * 16 + mrow, kq);
            bl[t] = read_frag(Bl, wn + t * 16 + mrow, kq);
        }
#pragma unroll
        for (int mt = 0; mt < 4; mt++)
#pragma unroll
            for (int nt = 0; nt < 4; nt++) {
                acc[mt][nt] = __builtin_amdgcn_mfma_f32_16x16x32_bf16(ah[mt], bh[nt], acc[mt][nt], 0, 0, 0);
                acc[mt][nt] = __builtin_amdgcn_mfma_f32_16x16x32_bf16(ah[mt], bl[nt], acc[mt][nt], 0, 0, 0);
                acc[mt][nt] = __builtin_amdgcn_mfma_f32_16x16x32_bf16(al[mt], bh[nt], acc[mt][nt], 0, 0, 0);
            }
    }
#pragma unroll
    for (int mt = 0; mt < 4; mt++)
#pragma unroll
        for (int nt = 0; nt < 4; nt++)
#pragma unroll
            for (int i = 0; i < 4; i++) {
                int row = bm * 128 + wm + mt * 16 + (lane >> 4) * 4 + i;
                int col = bn * 128 + wn + nt * 16 + (lane & 15);
                unsigned short h, l; split2(acc[mt][nt][i], h, l);
                Chi[(size_t)row * EMBED + col] = h;
                Clo[(size_t)row * EMBED + col] = l;
            }
}

// ---------------- scan: m201-faithful 8-phase. 256q x 256k block, 512 thr, 8 waves (2q x 4k) ----------------
// r13-r18 ledger: every 2-barrier variant = 213-250us (pipes serialized, m233 stall). r17's
// counted-vmcnt failed with the WRONG phase anatomy (reads after a single barrier per step).
// This is the m201 recipe exactly: per phase { ds_read subtile ∥ 2 gll stage -> sched-pin ->
// s_barrier -> lgkmcnt(0) -> sched-pin (rule 18) -> setprio(1) 16-MFMA setprio(0) -> barrier },
// vmcnt counted ONCE per K=32 unit, placed BEFORE that phase's closing barrier (vmcnt is
// per-wave: wait-then-barrier is what publishes other waves' staged data). 4-unit LDS
// rotation (132 KB, 1 blk/CU — m201 itself runs 1 blk/CU at 1563 TF), stage 3 units ahead,
// vmcnt(8) steady (units u+2,u+3 in flight), tail 8->4->0. B-frags (X side) held in regs
// across the unit's 2 phases; per-phase ds_read = 4 A-frags (+4 B in phase 0).
template<int PH, bool ST, int VM>
static __device__ __forceinline__ void scan_phase(
    const unsigned short (*Tu)[32], const unsigned short (*Xu)[32],
    unsigned short (*Sn)[32], const unsigned short* Sg,
    int goff, int loff, int wq, int wk, int mrow, int kq,
    bf16x8 (&bh)[4], f32x4 (&acc)[8][4]) {
    bf16x8 ah[4];
#pragma unroll
    for (int t = 0; t < 4; t++)
        ah[t] = read_frag(Tu, wq + (PH * 4 + t) * 16 + mrow, kq);
    if (PH == 0) {
#pragma unroll
        for (int n = 0; n < 4; n++)
            bh[n] = read_frag(Xu, wk + n * 16 + mrow, kq);
    }
    if (ST) {
        gll(Sg + goff, (unsigned short*)Sn + loff);
        gll(Sg + goff + 128 * EMBED, (unsigned short*)Sn + loff + 128 * 32);
    }
    __builtin_amdgcn_sched_barrier(0);      // pin reads+stage above the barrier
    __builtin_amdgcn_s_barrier();
    asm volatile("s_waitcnt lgkmcnt(0)" ::: "memory");
    __builtin_amdgcn_sched_barrier(0);      // rule 18: MFMA may not hoist above the wait
    __builtin_amdgcn_s_setprio(1);
#pragma unroll
    for (int t = 0; t < 4; t++)
#pragma unroll
        for (int n = 0; n < 4; n++)
            acc[PH * 4 + t][n] = __builtin_amdgcn_mfma_f32_16x16x32_bf16(ah[t], bh[n], acc[PH * 4 + t][n], 0, 0, 0);
    __builtin_amdgcn_s_setprio(0);
    if (PH == 1) {
        if (VM == 8)      asm volatile("s_waitcnt vmcnt(8)" ::: "memory");
        else if (VM == 4) asm volatile("s_waitcnt vmcnt(4)" ::: "memory");
        else if (VM == 0) asm volatile("s_waitcnt vmcnt(0)" ::: "memory");
    }
    __builtin_amdgcn_s_barrier();
    asm volatile("" ::: "memory");
}

__global__ __launch_bounds__(512, 2) void k_scan(
    const unsigned short* __restrict__ Thi, const unsigned short* __restrict__ Xhi,
    int* __restrict__ cnt, int2* __restrict__ cand) {
    __shared__ unsigned short Tt[4][256][32];   // 64 KB
    __shared__ unsigned short Xt[4][256][32];   // 64 KB
    __shared__ float rowmax_[4][2][128];        // 4 KB

    int bid = blockIdx.x;            // 0..1023
    int x   = bid & 7;               // XCD id: owns 2 fixed 256-key super-tiles per batch
    int i   = bid >> 3;
    int kb2 = x * 2 + (i & 1);       // 0..15
    int qb  = (i >> 1) & 15;
    int b   = i >> 5;
    int tid = threadIdx.x, wave = tid >> 6, lane = tid & 63;
    int wr = wave >> 2, wc = wave & 3;
    int wq = wr * 128, wk = wc * 64;
    int mrow = lane & 15, kq = (lane >> 4) * 8;
    size_t qrow0 = (size_t)b * SEQ + (size_t)qb * 256;
    size_t krow0 = (size_t)b * SEQ + (size_t)kb2 * 256;
    const unsigned short* Tbase = Thi + qrow0 * EMBED;
    const unsigned short* Xbase = Xhi + krow0 * EMBED;

    // per-lane staging offsets (512-thread linear index; 4-segment swizzle, r17-verified)
    int r = tid >> 2, s = tid & 3, g = (s - (r >> 1)) & 3;
    int goff = r * EMBED + g * 8;
    int loff = r * 32 + s * 8;

    f32x4 zero = {0.f, 0.f, 0.f, 0.f};
    f32x4 acc[8][4];
#pragma unroll
    for (int a = 0; a < 8; a++)
#pragma unroll
        for (int n = 0; n < 4; n++) acc[a][n] = zero;
    bf16x8 bh[4];

    // prologue: stage units 0,1,2 (12 loads/wave); wait unit 0's 4 (vmcnt 8), publish
    gll(Tbase + goff,       (unsigned short*)Tt[0] + loff);
    gll(Tbase + goff + 128 * EMBED, (unsigned short*)Tt[0] + loff + 128 * 32);
    gll(Xbase + goff,       (unsigned short*)Xt[0] + loff);
    gll(Xbase + goff + 128 * EMBED, (unsigned short*)Xt[0] + loff + 128 * 32);
    gll(Tbase + 32 + goff,  (unsigned short*)Tt[1] + loff);
    gll(Tbase + 32 + goff + 128 * EMBED, (unsigned short*)Tt[1] + loff + 128 * 32);
    gll(Xbase + 32 + goff,  (unsigned short*)Xt[1] + loff);
    gll(Xbase + 32 + goff + 128 * EMBED, (unsigned short*)Xt[1] + loff + 128 * 32);
    gll(Tbase + 64 + goff,  (unsigned short*)Tt[2] + loff);
    gll(Tbase + 64 + goff + 128 * EMBED, (unsigned short*)Tt[2] + loff + 128 * 32);
    gll(Xbase + 64 + goff,  (unsigned short*)Xt[2] + loff);
    gll(Xbase + 64 + goff + 128 * EMBED, (unsigned short*)Xt[2] + loff + 128 * 32);
    asm volatile("s_waitcnt vmcnt(8)" ::: "memory");
    __builtin_amdgcn_s_barrier();
    asm volatile("" ::: "memory");

    const unsigned short* Tg = Tbase + 96;   // next unit to stage (unit 3)
    const unsigned short* Xg = Xbase + 96;

#define UNIT(U, STG, VM) do { \
        scan_phase<0, STG, VM>(Tt[U], Xt[U], Tt[(U + 3) & 3], Tg, goff, loff, wq, wk, mrow, kq, bh, acc); \
        scan_phase<1, STG, VM>(Tt[U], Xt[U], Xt[(U + 3) & 3], Xg, goff, loff, wq, wk, mrow, kq, bh, acc); \
        if (STG) { Tg += 32; Xg += 32; } \
    } while (0)

    for (int it = 0; it < 7; it++) {         // units 0..27, staging 3..30
        UNIT(0, true, 8);
        UNIT(1, true, 8);
        UNIT(2, true, 8);
        UNIT(3, true, 8);
    }
    UNIT(0, true, 8);    // unit 28: stages unit 31
    UNIT(1, false, 4);   // unit 29
    UNIT(2, false, 0);   // unit 30
    UNIT(3, false, -1);  // unit 31
#undef UNIT

    // ---- epilogue pass 1: per-row max over this wave's 64 keys -> LDS exchange ----
#pragma unroll
    for (int a = 0; a < 8; a++)
#pragma unroll
        for (int i2 = 0; i2 < 4; i2++) {
            float v = -INFINITY;
#pragma unroll
            for (int n = 0; n < 4; n++) v = fmaxf(v, acc[a][n][i2]);
#pragma unroll
            for (int d = 1; d < 16; d <<= 1) v = fmaxf(v, __shfl_xor(v, d));
            if ((lane & 15) == 0)
                rowmax_[wc][wr][a * 16 + (lane >> 4) * 4 + i2] = v;
        }
    __syncthreads();
    // ---- epilogue pass 2: threshold over the block's FULL 256 keys; emit candidates ----
    // (window >= proven 128: capture set still superset of {s >= global_max - TSCAN_U};
    //  larger windows only REDUCE counts -> CAP safer. r17-verified passing.)
#pragma unroll
    for (int a = 0; a < 8; a++)
#pragma unroll
        for (int i2 = 0; i2 < 4; i2++) {
            int lr = a * 16 + (lane >> 4) * 4 + i2;
            float th = fmaxf(fmaxf(rowmax_[0][wr][lr], rowmax_[1][wr][lr]),
                             fmaxf(rowmax_[2][wr][lr], rowmax_[3][wr][lr])) - TSCAN_U;
            int grow = (int)qrow0 + wq + lr;
#pragma unroll
            for (int n = 0; n < 4; n++) {
                float sc = acc[a][n][i2];
                if (sc >= th) {
                    int gcol = (int)krow0 + wk + n * 16 + (lane & 15);
                    int idx = atomicAdd(&cnt[grow], 1);
                    if (idx < CAP)
                        cand[(size_t)grow * CAP + idx] = make_int2(gcol, __float_as_int(sc * 0.03125f));
                }
            }
        }
}

// ---------------- rescore: 4 rows per block, one wave per row, barrier-free ----------------
__global__ __launch_bounds__(256) void k_rescore(
    const unsigned short* __restrict__ Thi, const unsigned short* __restrict__ Tlo,
    const float* __restrict__ X, const float* __restrict__ vmean,
    const int* __restrict__ cnt, const int2* __restrict__ cand,
    float* __restrict__ out) {
    int wave = threadIdx.x >> 6, lane = threadIdx.x & 63;
    int row = blockIdx.x * 4 + wave;
    int c = cnt[row]; if (c > CAP) c = CAP;
    const int2* cl = cand + (size_t)row * CAP;

    float smax = -INFINITY;
    for (int j = lane; j < c; j += 64) smax = fmaxf(smax, __int_as_float(cl[j].y));
    for (int d = 1; d < 64; d <<= 1) smax = fmaxf(smax, __shfl_xor(smax, d));
    float th = smax - TRES;

    float q[16];
    {
        const unsigned short* qh = Thi + (size_t)row * EMBED + lane * 16;
        const unsigned short* ql = Tlo + (size_t)row * EMBED + lane * 16;
        bf16x8 h0 = *(const bf16x8*)qh, h1 = *(const bf16x8*)(qh + 8);
        bf16x8 l0 = *(const bf16x8*)ql, l1 = *(const bf16x8*)(ql + 8);
#pragma unroll
        for (int i = 0; i < 8; i++) {
            q[i]     = bf2f((unsigned short)h0[i]) + bf2f((unsigned short)l0[i]);
            q[i + 8] = bf2f((unsigned short)h1[i]) + bf2f((unsigned short)l1[i]);
        }
    }

    __shared__ int   sm_[4][CAP];
    __shared__ float sl_[4][CAP];
    __shared__ int   ns_[4];
    if (lane == 0) ns_[wave] = 0;
    for (int j = lane; j < c; j += 64) {
        int2 p = cl[j];
        if (__int_as_float(p.y) >= th) {
            int idx = atomicAdd(&ns_[wave], 1);
            sm_[wave][idx] = p.x;
        }
    }
    int ns = ns_[wave];
    for (int t = 0; t < ns; t++) {
        int m = sm_[wave][t];
        const float* xr = X + (size_t)m * EMBED + lane * 16;
        float4 a0 = *(const float4*)(xr);
        float4 a1 = *(const float4*)(xr + 4);
        float4 a2 = *(const float4*)(xr + 8);
        float4 a3 = *(const float4*)(xr + 12);
        float dp = q[0]*a0.x + q[1]*a0.y + q[2]*a0.z + q[3]*a0.w
                 + q[4]*a1.x + q[5]*a1.y + q[6]*a1.z + q[7]*a1.w
                 + q[8]*a2.x + q[9]*a2.y + q[10]*a2.z + q[11]*a2.w
                 + q[12]*a3.x + q[13]*a3.y + q[14]*a3.z + q[15]*a3.w;
        for (int d = 1; d < 64; d <<= 1) dp += __shfl_xor(dp, d);
        if (lane == 0) sl_[wave][t] = dp * 0.03125f;
    }
    if (lane == 0) {
        float lm = -INFINITY;
        for (int t = 0; t < ns; t++) lm = fmaxf(lm, sl_[wave][t]);
        float den = 0.f, num = 0.f;
        for (int t = 0; t < ns; t++) {
            float e = __expf(sl_[wave][t] - lm);
            den += e;
            num += e * vmean[sm_[wave][t]];
        }
        out[row] = num / den;
    }
}

extern "C" void kernel_launch(void* const* d_in, const int* in_sizes, int n_in,
                              void* d_out, int out_size, void* d_ws, size_t ws_size,
                              hipStream_t stream) {
    const float* X  = (const float*)d_in[0];
    const float* Wq = (const float*)d_in[1];
    const float* Wk = (const float*)d_in[2];
    const float* Wv = (const float*)d_in[3];
    float* out = (float*)d_out;

    char* p = (char*)d_ws;
    auto alloc = [&](size_t bytes) -> void* {
        void* q = (void*)p;
        p += (bytes + 255) & ~(size_t)255;
        return q;
    };
    unsigned short* Wqhi = (unsigned short*)alloc((size_t)EMBED * EMBED * 2);
    unsigned short* Wqlo = (unsigned short*)alloc((size_t)EMBED * EMBED * 2);
    unsigned short* Wkhi = (unsigned short*)alloc((size_t)EMBED * EMBED * 2);
    unsigned short* Wklo = (unsigned short*)alloc((size_t)EMBED * EMBED * 2);
    unsigned short* MThi = (unsigned short*)alloc((size_t)EMBED * EMBED * 2);
    unsigned short* MTlo = (unsigned short*)alloc((size_t)EMBED * EMBED * 2);
    unsigned short* Xhi  = (unsigned short*)alloc((size_t)ROWS * EMBED * 2);
    unsigned short* Xlo  = (unsigned short*)alloc((size_t)ROWS * EMBED * 2);
    unsigned short* Thi  = (unsigned short*)alloc((size_t)ROWS * EMBED * 2);
    unsigned short* Tlo  = (unsigned short*)alloc((size_t)ROWS * EMBED * 2);
    float* wvbar = (float*)alloc(EMBED * 4);
    float* vmean = (float*)alloc((size_t)ROWS * 4);
    int*   cnt   = (int*)alloc((size_t)ROWS * 4);
    int2*  cand  = (int2*)alloc((size_t)ROWS * CAP * 8);

    k_wvbar<<<EMBED, 256, 0, stream>>>(Wv, wvbar);
    // Row splits of the ORIGINAL Wq/Wk (M contraction is over the contiguous output dim).
    // vmean/cnt args are scratch here (rows 0..1023; real run below overwrites all rows).
    k_xsplit_vmean<<<EMBED, 256, 0, stream>>>(Wq, wvbar, Wqhi, Wqlo, vmean, cnt);
    k_xsplit_vmean<<<EMBED, 256, 0, stream>>>(Wk, wvbar, Wkhi, Wklo, vmean, cnt);
    // M^T[b][a] = sum_n Wk[b][n]*Wq[a][n]
    k_gemm3<<<64, 256, 0, stream>>>(Wkhi, Wklo, Wqhi, Wqlo, MThi, MTlo);
    k_xsplit_vmean<<<ROWS, 256, 0, stream>>>(X, wvbar, Xhi, Xlo, vmean, cnt);  // real vmean + cnt=0
    k_gemm3<<<1024, 256, 0, stream>>>(Xhi, Xlo, MThi, MTlo, Thi, Tlo);         // T = X.M
    k_scan<<<1024, 512, 0, stream>>>(Thi, Xhi, cnt, cand);
    k_rescore<<<ROWS / 4, 256, 0, stream>>>(Thi, Tlo, X, vmean, cnt, cand, out);
}